// Round 6
// baseline (136.345 us; speedup 1.0000x reference)
//
#include <hip/hip_runtime.h>
#include <math.h>

// ECE loss: per-row softmax-max confidence + argmax prediction, histogram over
// (pred_class, conf_bin) cells, ECE = sum|sum_conf - sum_acc| / N.
//
// Round-6: DEPTH-3 PREFETCH (the one axis r3/r4/r5 never had; all were
// depth-1 and stalled at the waitcnt every tile since request arrival under
// load ~3-6k cyc > consume ~1.5k cyc). m201 discipline: 4 LDS buffers,
// every wave issues exactly 2 global_load_lds per tile, steady-state
// s_waitcnt vmcnt(6) = 3 tiles x 2 loads always in flight, raw s_barrier
// (no vmcnt drain).
//
// 512-thread blocks, 32-row tiles. Per buffer 1024 chunks (16 KB):
//   [0 .. 864)     32 rows x 27 chunks (25 payload + 2 pad -> clamped dups)
//   [864 .. 872)   32 labels (int32)
//   [872 .. 1024)  dups of tile chunk 0 (exec-uniform issue, L1/L2 hits)
// 4 buffers (64 KB) + 12 KB hist = 77.5 KB -> 2 blocks/CU, 16 waves/CU.
// In flight per CU: 2 blocks x 3 tiles x 16 KB ~ 96 KB >> latency x rate.
//
// N = 1,000,000 = 32 * 31250 exactly.
// Workspace (d_ws as float*): [0..NCELLS) sum_conf, [NCELLS..2*NCELLS) sum_acc.

constexpr int C  = 100;
constexpr int NB = 15;
constexpr int NCELLS = C * NB;        // 1500
constexpr int ROWS = 32;              // rows per tile
constexpr int CHR  = 27;              // LDS chunks (16B) per row
constexpr int PAY_CH  = ROWS * CHR;   // 864
constexpr int LAB_CH0 = PAY_CH;       // 864..871: 32 labels
constexpr int BUF_CH  = 1024;         // buffer size in chunks (16 KB)
constexpr int NBUF = 4;
constexpr int THREADS = 512;
constexpr int GRID_MAIN = 512;        // 2 blocks/CU x 256 CU

__global__ void ece_zero(float* __restrict__ ws, int n) {
    int i = blockIdx.x * blockDim.x + threadIdx.x;
    if (i < n) ws[i] = 0.0f;
}

__device__ __forceinline__ void load_lds_16B(const void* gsrc, void* ldst) {
    __builtin_amdgcn_global_load_lds(
        (const __attribute__((address_space(1))) void*)gsrc,
        (__attribute__((address_space(3))) void*)ldst, 16, 0, 0);
}

__global__ __launch_bounds__(THREADS)
void ece_main(const float* __restrict__ logits,
              const int* __restrict__ labels,
              int ntiles, float* __restrict__ cellsums) {
    __shared__ float4 stage[NBUF][BUF_CH];   // 65536 B
    __shared__ float  hist[2 * NCELLS];      // 12000 B -> 77.5 KB total

    for (int i = threadIdx.x; i < 2 * NCELLS; i += THREADS) hist[i] = 0.0f;
    __syncthreads();

    const int tid = threadIdx.x;
    const int h   = tid >> 4;   // row in tile (0..31)
    const int l   = tid & 15;   // lane within hex group

    // ---- per-lane stage descriptors (tile-invariant byte offsets) ----
    // chunk c0 = tid (0..511): always payload
    int r0 = tid / CHR, c0c = tid - r0 * CHR;
    if (c0c > 24) c0c = 24;
    const int off0 = r0 * (C * 4) + c0c * 16;
    // chunk c1 = 512 + tid: payload (tid<352) | label chunk | dup of chunk 0
    const int c1 = 512 + tid;
    int off1; bool isLab1 = false;
    if (c1 < PAY_CH) {
        int r = c1 / CHR, cc = c1 - r * CHR;
        if (cc > 24) cc = 24;
        off1 = r * (C * 4) + cc * 16;
    } else if (c1 < LAB_CH0 + 8) {
        isLab1 = true;
        off1 = (c1 - LAB_CH0) * 16;     // bytes into this tile's labels
    } else {
        off1 = 0;                        // dup: tile payload chunk 0
    }
    const size_t dst0 = (size_t)(tid & ~63) * 16;  // wave-uniform LDS base

    const char* const lg = (const char*)logits;
    const char* const lb = (const char*)labels;
    constexpr float LOG2E = 1.4426950408889634f;

#define ISSUE_STAGE(T, BUF)                                                   \
    {                                                                         \
        const char* tb_ = lg + (size_t)(T) * (ROWS * C * 4);                  \
        const char* lt_ = lb + (size_t)(T) * (ROWS * 4);                      \
        char* d_ = (char*)&stage[(BUF)][0] + dst0;                            \
        load_lds_16B(tb_ + off0, d_);                                         \
        load_lds_16B(isLab1 ? (lt_ + off1) : (tb_ + off1), d_ + 512 * 16);    \
    }

    // ---- prologue: fill pipeline to depth 3 ----
    int t = blockIdx.x;
    if (t < ntiles)                 ISSUE_STAGE(t, 0);
    if (t + GRID_MAIN < ntiles)     ISSUE_STAGE(t + GRID_MAIN, 1);
    if (t + 2 * GRID_MAIN < ntiles) ISSUE_STAGE(t + 2 * GRID_MAIN, 2);

    int cur = 0;
    for (; t < ntiles; t += GRID_MAIN) {
        const int tn = t + 3 * GRID_MAIN;
        if (tn < ntiles) {
            ISSUE_STAGE(tn, (cur + 3) & 3);
            // oldest 2 (tile t's) done; 6 (tiles t+1G,t+2G,t+3G) stay in flight
            asm volatile("s_waitcnt vmcnt(6)" ::: "memory");
        } else {
            asm volatile("s_waitcnt vmcnt(0)" ::: "memory");
        }
        __builtin_amdgcn_s_barrier();      // all waves' tile-t loads landed
        __builtin_amdgcn_sched_barrier(0);

        // ---- consume tile t from stage[cur]: hex (16 lanes) per row ----
        const float4* rp = &stage[cur][h * CHR];
        float4 a = rp[l];                  // chunks 0..15 -> elems 4l..4l+3
        float4 b4;
        const bool two = (l < 9);          // chunks 16..24 -> elems 64+4l..
        if (two) b4 = rp[16 + l];
        int lab = -1;
        if (l == 0) lab = ((const int*)&stage[cur][LAB_CH0])[h];

        float m = a.x; int am = 4 * l;
        if (a.y > m) { m = a.y; am = 4 * l + 1; }
        if (a.z > m) { m = a.z; am = 4 * l + 2; }
        if (a.w > m) { m = a.w; am = 4 * l + 3; }
        if (two) {
            const int e = 64 + 4 * l;
            if (b4.x > m) { m = b4.x; am = e; }
            if (b4.y > m) { m = b4.y; am = e + 1; }
            if (b4.z > m) { m = b4.z; am = e + 2; }
            if (b4.w > m) { m = b4.w; am = e + 3; }
        }
        #pragma unroll
        for (int off = 1; off < 16; off <<= 1) {
            float om  = __shfl_xor(m, off, 64);
            int   oam = __shfl_xor(am, off, 64);
            if (om > m || (om == m && oam < am)) { m = om; am = oam; }
        }

        const float ml = m * LOG2E;
        float s = exp2f(__fmaf_rn(a.x, LOG2E, -ml))
                + exp2f(__fmaf_rn(a.y, LOG2E, -ml))
                + exp2f(__fmaf_rn(a.z, LOG2E, -ml))
                + exp2f(__fmaf_rn(a.w, LOG2E, -ml));
        if (two) {
            s += exp2f(__fmaf_rn(b4.x, LOG2E, -ml))
               + exp2f(__fmaf_rn(b4.y, LOG2E, -ml))
               + exp2f(__fmaf_rn(b4.z, LOG2E, -ml))
               + exp2f(__fmaf_rn(b4.w, LOG2E, -ml));
        }
        #pragma unroll
        for (int off = 1; off < 16; off <<= 1) s += __shfl_xor(s, off, 64);

        if (l == 0) {
            float conf = 1.0f / s;
            int b = (int)ceilf(conf * (float)NB) - 1;
            b = b < 0 ? 0 : (b > NB - 1 ? NB - 1 : b);
            int cell = am * NB + b;
            atomicAdd(&hist[cell], conf);
            if (lab == am) atomicAdd(&hist[NCELLS + cell], 1.0f);
        }

        // my reads of stage[cur] retired before tile t+4G overwrites it
        asm volatile("s_waitcnt lgkmcnt(0)" ::: "memory");
        __builtin_amdgcn_sched_barrier(0);
        __builtin_amdgcn_s_barrier();
        cur = (cur + 1) & 3;
    }
#undef ISSUE_STAGE

    __syncthreads();
    for (int i = threadIdx.x; i < 2 * NCELLS; i += THREADS) {
        float v = hist[i];
        if (v != 0.0f) atomicAdd(&cellsums[i], v);
    }
}

__global__ void ece_final(const float* __restrict__ cellsums,
                          float invN, float* __restrict__ out) {
    __shared__ float red[256];
    float t = 0.0f;
    for (int i = threadIdx.x; i < NCELLS; i += blockDim.x)
        t += fabsf(cellsums[i] - cellsums[NCELLS + i]);
    red[threadIdx.x] = t;
    __syncthreads();
    for (int w = 128; w > 0; w >>= 1) {
        if (threadIdx.x < w) red[threadIdx.x] += red[threadIdx.x + w];
        __syncthreads();
    }
    if (threadIdx.x == 0) out[0] = red[0] * invN;
}

extern "C" void kernel_launch(void* const* d_in, const int* in_sizes, int n_in,
                              void* d_out, int out_size, void* d_ws, size_t ws_size,
                              hipStream_t stream) {
    const float* logits = (const float*)d_in[0];
    const int*   labels = (const int*)d_in[1];

    const int N = in_sizes[1];                 // 1,000,000
    const int ntiles = N / ROWS;               // 31250 (exact)

    float* cellsums = (float*)d_ws;
    float* out = (float*)d_out;

    // 1) zero global cell accumulators (harness poisons ws, never re-zeroes)
    {
        int n = 2 * NCELLS;
        ece_zero<<<(n + 255) / 256, 256, 0, stream>>>(cellsums, n);
    }

    // 2) main pass: depth-3 prefetch, counted vmcnt(6), raw barriers
    ece_main<<<GRID_MAIN, THREADS, 0, stream>>>(logits, labels, ntiles, cellsums);

    // 3) finalize
    ece_final<<<1, 256, 0, stream>>>(cellsums, 1.0f / (float)N, out);
}

// Round 8
// 113.395 us; speedup vs baseline: 1.2024x; 1.2024x over previous
//
#include <hip/hip_runtime.h>
#include <math.h>

// ECE loss: per-row softmax-max confidence + argmax prediction, histogram over
// (pred_class, conf_bin) cells, ECE = sum|sum_conf - sum_acc| / N.
//
// Round-8: round-7's reg-staged structure with its two bugs fixed:
//   (a) consume now covers all 64 rows (4 row-groups per hex group; r7 only
//       consumed rows 0..15 with 256 threads),
//   (b) load/write instr #6 correctly sized: payload lanes 0..63 (chunks
//       1536..1599), label lanes 64..79 (16 f4 = 64 labels), rest inactive
//       (r7 had 128 payload lanes -> ldsa=-1 OOB LDS writes).
//
// Structure (T14 reg-staging, plain global_load_dwordx4 path - the m13
// 6.29 TB/s pattern; no global_load_lds anywhere):
//   loop:  __syncthreads            (prev consume done; my loads arrived)
//          ds_write regs -> LDS     (tile t visible)
//          __syncthreads
//          issue 7 loads of tile t+1 (contiguous float4)
//          consume tile t from LDS   (overlaps in-flight loads)
// Tile = 64 rows x 100 floats = 1600 f4 (25.6 KB). LDS rows padded to 27 f4.
// 27.3 KB tile + 12 KB hist = 39.9 KB -> 4 blocks/CU, 16 waves/CU.
// In flight per CU at issue: 4 blocks x ~28 KB = 112 KB.
//
// N = 1,000,000 = 64 * 15625 exactly; label chunks: 15624*16+15 = 249999 in range.
// Workspace (d_ws as float*): [0..NCELLS) sum_conf, [NCELLS..2*NCELLS) sum_acc.

constexpr int C  = 100;
constexpr int NB = 15;
constexpr int NCELLS = C * NB;        // 1500
constexpr int ROWS = 64;              // rows per tile
constexpr int F4R  = 25;              // float4 per row
constexpr int STR  = 27;              // padded LDS row stride (f4)
constexpr int PAY  = ROWS * F4R;      // 1600 payload f4 per tile
constexpr int LAB0 = ROWS * STR;      // 1728: label area start (16 f4)
constexpr int THREADS = 256;
constexpr int GRID_MAIN = 1024;       // 4 blocks/CU x 256 CU

__global__ void ece_zero(float* __restrict__ ws, int n) {
    int i = blockIdx.x * blockDim.x + threadIdx.x;
    if (i < n) ws[i] = 0.0f;
}

__global__ __launch_bounds__(THREADS)
void ece_main(const float* __restrict__ logits,
              const int* __restrict__ labels,
              int ntiles, float* __restrict__ cellsums) {
    __shared__ float4 tilebuf[LAB0 + 16];   // 1744 f4 = 27904 B
    __shared__ float  hist[2 * NCELLS];     // 12000 B -> 39.9 KB total

    for (int i = threadIdx.x; i < 2 * NCELLS; i += THREADS) hist[i] = 0.0f;
    __syncthreads();

    const int tid = threadIdx.x;
    const int h   = tid >> 4;   // hex group 0..15; handles rows h,h+16,h+32,h+48
    const int l   = tid & 15;   // lane within hex group

    // ---- tile-invariant descriptors ----
    // payload chunk k -> LDS f4 addr k + 2*(k/25)  (stride-27 padding)
    int ldsa[6];
    #pragma unroll
    for (int i = 0; i < 6; ++i) {
        int k = i * 256 + tid;              // < 1536 < PAY: always payload
        ldsa[i] = k + 2 * (k / F4R);
    }
    const int  k6     = 1536 + tid;
    const bool pay6   = (tid < PAY - 1536);            // lanes 0..63
    const bool isLab  = (tid >= 64 && tid < 80);       // label lanes
    int lds6 = 0;
    if (pay6)       lds6 = k6 + 2 * (k6 / F4R);
    else if (isLab) lds6 = LAB0 + (tid - 64);
    const bool act6 = pay6 || isLab;

    const float4* const lg4 = reinterpret_cast<const float4*>(logits);
    const float4* const lb4 = reinterpret_cast<const float4*>(labels);
    constexpr float LOG2E = 1.4426950408889634f;

    float4 g0, g1, g2, g3, g4, g5, g6;

#define ISSUE(T)                                                              \
    {                                                                         \
        const float4* tb_ = lg4 + (size_t)(T) * PAY;                          \
        g0 = tb_[tid];                                                        \
        g1 = tb_[256 + tid];                                                  \
        g2 = tb_[512 + tid];                                                  \
        g3 = tb_[768 + tid];                                                  \
        g4 = tb_[1024 + tid];                                                 \
        g5 = tb_[1280 + tid];                                                 \
        if (pay6)       g6 = tb_[1536 + tid];                                 \
        else if (isLab) g6 = lb4[(size_t)(T) * 16 + (tid - 64)];              \
    }

    int t = blockIdx.x;
    if (t < ntiles) ISSUE(t);            // prologue: tile t in flight

    for (; t < ntiles; t += GRID_MAIN) {
        __syncthreads();                 // prev consume done; my loads landed

        // regs -> LDS
        tilebuf[ldsa[0]] = g0;
        tilebuf[ldsa[1]] = g1;
        tilebuf[ldsa[2]] = g2;
        tilebuf[ldsa[3]] = g3;
        tilebuf[ldsa[4]] = g4;
        tilebuf[ldsa[5]] = g5;
        if (act6) tilebuf[lds6] = g6;
        __syncthreads();                 // tile t visible to all

        const int tn = t + GRID_MAIN;
        if (tn < ntiles) ISSUE(tn);      // issue early; lands during consume

        // ---- consume tile t: hex (16 lanes) per row, 4 rows per group ----
        #pragma unroll
        for (int rr = 0; rr < 4; ++rr) {
            const int row = h + rr * 16;
            const float4* rp = &tilebuf[row * STR];
            float4 a = rp[l];            // chunks 0..15 -> elems 4l..4l+3
            float4 b4;
            const bool two = (l < 9);    // chunks 16..24 -> elems 64+4l..
            if (two) b4 = rp[16 + l];
            int lab = -1;
            if (l == 0) lab = ((const int*)&tilebuf[LAB0])[row];

            float m = a.x; int am = 4 * l;
            if (a.y > m) { m = a.y; am = 4 * l + 1; }
            if (a.z > m) { m = a.z; am = 4 * l + 2; }
            if (a.w > m) { m = a.w; am = 4 * l + 3; }
            if (two) {
                const int e = 64 + 4 * l;
                if (b4.x > m) { m = b4.x; am = e; }
                if (b4.y > m) { m = b4.y; am = e + 1; }
                if (b4.z > m) { m = b4.z; am = e + 2; }
                if (b4.w > m) { m = b4.w; am = e + 3; }
            }
            #pragma unroll
            for (int off = 1; off < 16; off <<= 1) {
                float om  = __shfl_xor(m, off, 64);
                int   oam = __shfl_xor(am, off, 64);
                if (om > m || (om == m && oam < am)) { m = om; am = oam; }
            }

            const float ml = m * LOG2E;
            float s = exp2f(__fmaf_rn(a.x, LOG2E, -ml))
                    + exp2f(__fmaf_rn(a.y, LOG2E, -ml))
                    + exp2f(__fmaf_rn(a.z, LOG2E, -ml))
                    + exp2f(__fmaf_rn(a.w, LOG2E, -ml));
            if (two) {
                s += exp2f(__fmaf_rn(b4.x, LOG2E, -ml))
                   + exp2f(__fmaf_rn(b4.y, LOG2E, -ml))
                   + exp2f(__fmaf_rn(b4.z, LOG2E, -ml))
                   + exp2f(__fmaf_rn(b4.w, LOG2E, -ml));
            }
            #pragma unroll
            for (int off = 1; off < 16; off <<= 1) s += __shfl_xor(s, off, 64);

            if (l == 0) {
                float conf = 1.0f / s;
                int b = (int)ceilf(conf * (float)NB) - 1;
                b = b < 0 ? 0 : (b > NB - 1 ? NB - 1 : b);
                int cell = am * NB + b;
                atomicAdd(&hist[cell], conf);
                if (lab == am) atomicAdd(&hist[NCELLS + cell], 1.0f);
            }
        }
        // next loop-top __syncthreads orders everyone's consume before the
        // regs->LDS overwrite, and waits my in-flight loads (T14)
    }
#undef ISSUE

    __syncthreads();
    for (int i = threadIdx.x; i < 2 * NCELLS; i += THREADS) {
        float v = hist[i];
        if (v != 0.0f) atomicAdd(&cellsums[i], v);
    }
}

__global__ void ece_final(const float* __restrict__ cellsums,
                          float invN, float* __restrict__ out) {
    __shared__ float red[256];
    float t = 0.0f;
    for (int i = threadIdx.x; i < NCELLS; i += blockDim.x)
        t += fabsf(cellsums[i] - cellsums[NCELLS + i]);
    red[threadIdx.x] = t;
    __syncthreads();
    for (int w = 128; w > 0; w >>= 1) {
        if (threadIdx.x < w) red[threadIdx.x] += red[threadIdx.x + w];
        __syncthreads();
    }
    if (threadIdx.x == 0) out[0] = red[0] * invN;
}

extern "C" void kernel_launch(void* const* d_in, const int* in_sizes, int n_in,
                              void* d_out, int out_size, void* d_ws, size_t ws_size,
                              hipStream_t stream) {
    const float* logits = (const float*)d_in[0];
    const int*   labels = (const int*)d_in[1];

    const int N = in_sizes[1];                 // 1,000,000
    const int ntiles = N / ROWS;               // 15625 (exact)

    float* cellsums = (float*)d_ws;
    float* out = (float*)d_out;

    // 1) zero global cell accumulators (harness poisons ws, never re-zeroes)
    {
        int n = 2 * NCELLS;
        ece_zero<<<(n + 255) / 256, 256, 0, stream>>>(cellsums, n);
    }

    // 2) main pass: reg-staged tiles, plain-load path, T14 issue-early
    ece_main<<<GRID_MAIN, THREADS, 0, stream>>>(logits, labels, ntiles, cellsums);

    // 3) finalize
    ece_final<<<1, 256, 0, stream>>>(cellsums, 1.0f / (float)N, out);
}

// Round 9
// 85.751 us; speedup vs baseline: 1.5900x; 1.3224x over previous
//
#include <hip/hip_runtime.h>
#include <math.h>

// ECE loss: per-row softmax-max confidence + argmax prediction, binned
// histogram over (pred_class, conf_bin) cells, ECE = sum|sum_conf-sum_acc|/N.
//
// Round-9 = round-3 (best: 93.6 us) + ONE change: staging loads marked
// NON-TEMPORAL (global_load_lds aux=2 -> CPol NT on gfx940+). The kernel
// streams 400 MB exactly once; L1/L2/L3 allocation of dead lines is pure
// overhead (the 256 MB L3 continuously evicts itself under the stream).
// Everything else identical to r3 for a clean A/B vs 93.6 us.
//
// Workspace (d_ws as float*): [0..NCELLS) sum_conf, [NCELLS..2*NCELLS) sum_acc.

constexpr int C  = 100;
constexpr int NB = 15;
constexpr int NCELLS = C * NB;          // 1500
constexpr int ROWS_PER_TILE = 64;
constexpr int F4_PER_ROW   = 25;        // 100 floats
constexpr int LDS_F4_STRIDE = 26;       // pad to 416 B for bank spread
constexpr int LDS_TILE_F4  = ROWS_PER_TILE * LDS_F4_STRIDE;  // 1664
constexpr int GRID_MAIN = 977;          // 4 blocks/CU resident; 15625 tiles

__global__ void ece_zero(float* __restrict__ ws, int n) {
    int i = blockIdx.x * blockDim.x + threadIdx.x;
    if (i < n) ws[i] = 0.0f;
}

__device__ __forceinline__ void load_lds_16B_nt(const void* gsrc, void* ldst) {
    // aux=2: CPol NT (non-temporal) on gfx940+/gfx950 — stream, evict-first.
    __builtin_amdgcn_global_load_lds(
        (const __attribute__((address_space(1))) void*)gsrc,
        (__attribute__((address_space(3))) void*)ldst, 16, 0, 2);
}

__global__ __launch_bounds__(256)
void ece_main(const float* __restrict__ logits,
              const int* __restrict__ labels,
              int N, int ntiles, float* __restrict__ cellsums) {
    __shared__ float4 stage[LDS_TILE_F4];   // 26624 B
    __shared__ float  hist[2 * NCELLS];     // 12000 B  (total 38.6 KB -> 4 blk/CU)

    for (int i = threadIdx.x; i < 2 * NCELLS; i += blockDim.x) hist[i] = 0.0f;

    const int tid  = threadIdx.x;
    const int l4   = tid & 3;
    const int qg   = tid >> 2;              // 0..63: row-in-tile owned by quad
    const int wbase = (tid >> 6) << 6;      // wave-uniform lane-0 tid
    const float4* logits4 = reinterpret_cast<const float4*>(logits);
    constexpr float LOG2E = 1.4426950408889634f;

    for (int tile = blockIdx.x; tile < ntiles; tile += gridDim.x) {
        const int row0 = tile * ROWS_PER_TILE;

        // ---- stage: contiguous global stream -> padded LDS tile (NT) ----
        // slot s holds (row r = s/26, f4-col c = s%26); c==25 is pad (skip).
        #pragma unroll
        for (int i = 0; i < 7; ++i) {
            int s = i * 256 + tid;
            if (s < LDS_TILE_F4) {
                int r = s / LDS_F4_STRIDE;
                int c = s - r * LDS_F4_STRIDE;
                if (c < F4_PER_ROW && (row0 + r) < N) {
                    const float4* g = logits4 + (size_t)(row0 + r) * F4_PER_ROW + c;
                    // LDS dst: wave-uniform base; HW adds lane*16
                    load_lds_16B_nt(g, &stage[i * 256 + wbase]);
                }
            }
        }
        __syncthreads();   // drains vmcnt -> tile staged

        // ---- consume: quad-per-row from LDS ----
        const int row = row0 + qg;
        if (row < N) {
            int lab = -1;
            if (l4 == 0) lab = labels[row];   // prefetch, overlaps compute

            const float4* rp = &stage[qg * LDS_F4_STRIDE];
            float4 v[6];
            #pragma unroll
            for (int j = 0; j < 6; ++j) v[j] = rp[l4 + 4 * j];
            float4 v6;
            const bool has7 = (l4 == 0);
            if (has7) v6 = rp[24];

            // pass 1: per-lane max + first-occurrence argmax
            float m = -INFINITY;
            int   am = 0;
            #pragma unroll
            for (int j = 0; j < 6; ++j) {
                int base = (l4 + 4 * j) * 4;
                if (v[j].x > m) { m = v[j].x; am = base + 0; }
                if (v[j].y > m) { m = v[j].y; am = base + 1; }
                if (v[j].z > m) { m = v[j].z; am = base + 2; }
                if (v[j].w > m) { m = v[j].w; am = base + 3; }
            }
            if (has7) {
                if (v6.x > m) { m = v6.x; am = 96; }
                if (v6.y > m) { m = v6.y; am = 97; }
                if (v6.z > m) { m = v6.z; am = 98; }
                if (v6.w > m) { m = v6.w; am = 99; }
            }
            #pragma unroll
            for (int off = 1; off < 4; off <<= 1) {
                float om  = __shfl_xor(m, off, 64);
                int   oam = __shfl_xor(am, off, 64);
                if (om > m || (om == m && oam < am)) { m = om; am = oam; }
            }

            // pass 2: sum exp(x-m) = exp2(x*log2e - m*log2e), fused fma+exp2
            const float ml = m * LOG2E;
            float s = 0.0f;
            #pragma unroll
            for (int j = 0; j < 6; ++j) {
                s += exp2f(__fmaf_rn(v[j].x, LOG2E, -ml))
                   + exp2f(__fmaf_rn(v[j].y, LOG2E, -ml))
                   + exp2f(__fmaf_rn(v[j].z, LOG2E, -ml))
                   + exp2f(__fmaf_rn(v[j].w, LOG2E, -ml));
            }
            if (has7) {
                s += exp2f(__fmaf_rn(v6.x, LOG2E, -ml))
                   + exp2f(__fmaf_rn(v6.y, LOG2E, -ml))
                   + exp2f(__fmaf_rn(v6.z, LOG2E, -ml))
                   + exp2f(__fmaf_rn(v6.w, LOG2E, -ml));
            }
            #pragma unroll
            for (int off = 1; off < 4; off <<= 1) s += __shfl_xor(s, off, 64);

            if (l4 == 0) {
                float conf = 1.0f / s;
                int b = (int)ceilf(conf * (float)NB) - 1;
                b = b < 0 ? 0 : (b > NB - 1 ? NB - 1 : b);
                int cell = am * NB + b;
                atomicAdd(&hist[cell], conf);
                if (lab == am) atomicAdd(&hist[NCELLS + cell], 1.0f);
            }
        }
        __syncthreads();   // protect stage buffer before next overwrite
    }

    // flush per-block histogram
    for (int i = threadIdx.x; i < 2 * NCELLS; i += blockDim.x) {
        float v = hist[i];
        if (v != 0.0f) atomicAdd(&cellsums[i], v);
    }
}

__global__ void ece_final(const float* __restrict__ cellsums,
                          float invN, float* __restrict__ out) {
    __shared__ float red[256];
    float t = 0.0f;
    for (int i = threadIdx.x; i < NCELLS; i += blockDim.x)
        t += fabsf(cellsums[i] - cellsums[NCELLS + i]);
    red[threadIdx.x] = t;
    __syncthreads();
    for (int w = 128; w > 0; w >>= 1) {
        if (threadIdx.x < w) red[threadIdx.x] += red[threadIdx.x + w];
        __syncthreads();
    }
    if (threadIdx.x == 0) out[0] = red[0] * invN;
}

extern "C" void kernel_launch(void* const* d_in, const int* in_sizes, int n_in,
                              void* d_out, int out_size, void* d_ws, size_t ws_size,
                              hipStream_t stream) {
    const float* logits = (const float*)d_in[0];
    const int*   labels = (const int*)d_in[1];

    const int N = in_sizes[1];  // 1,000,000 rows; C fixed 100, NB fixed 15
    const int ntiles = (N + ROWS_PER_TILE - 1) / ROWS_PER_TILE;  // 15625

    float* cellsums = (float*)d_ws;  // 2*NCELLS floats
    float* out = (float*)d_out;

    // 1) zero global cell accumulators (harness poisons ws, never re-zeroes)
    {
        int n = 2 * NCELLS;
        ece_zero<<<(n + 255) / 256, 256, 0, stream>>>(cellsums, n);
    }

    // 2) main pass (identical to r3 except NT staging loads)
    ece_main<<<GRID_MAIN, 256, 0, stream>>>(logits, labels, N, ntiles, cellsums);

    // 3) finalize
    ece_final<<<1, 256, 0, stream>>>(cellsums, 1.0f / (float)N, out);
}